// Round 1
// baseline (191.224 us; speedup 1.0000x reference)
//
#include <hip/hip_runtime.h>
#include <stdint.h>

#define B_ 32
#define E_ 256
#define L_ 2048
#define D_ 256

#define BE 64
#define BD 128
#define BK 64
#define NKT (L_ / BK)   // 32 k-tiles

typedef __attribute__((ext_vector_type(4))) float  f32x4;
typedef __attribute__((ext_vector_type(4))) short  s16x4;
typedef __attribute__((ext_vector_type(8))) short  s16x8;

// fp32 -> (hi, lo) bf16 pair. hi = truncated bf16(x); lo = bf16(x - hi).
// lo exactly compensates hi's truncation, so residual ~2^-16 relative.
__device__ __forceinline__ void cvt_hilo4(const f32x4 v, s16x4 &h, s16x4 &l) {
    #pragma unroll
    for (int i = 0; i < 4; ++i) {
        unsigned u = __builtin_bit_cast(unsigned, (float)v[i]);
        h[i] = (short)(u >> 16);
        float hf = __builtin_bit_cast(float, u & 0xFFFF0000u);
        unsigned r = __builtin_bit_cast(unsigned, (float)(v[i] - hf));
        l[i] = (short)(r >> 16);
    }
}

__global__ __launch_bounds__(512, 2)
void mean_pool_kernel(const float* __restrict__ doc,
                      const float* __restrict__ emap,
                      const float* __restrict__ lens,
                      float* __restrict__ out) {
    // k-group XOR swizzle instead of padding: A keyed on (row&7), B on ((row>>2)&7)
    __shared__ __align__(16) short As_hi[BE][BK];
    __shared__ __align__(16) short As_lo[BE][BK];
    __shared__ __align__(16) short Bs_hi[BD][BK];   // stores doc^T tile: [d][k]
    __shared__ __align__(16) short Bs_lo[BD][BK];
    __shared__ float lens_s[BE];

    const int t   = threadIdx.x;
    const int blk = blockIdx.x;
    const int b   = blk >> 3;
    const int e0  = ((blk >> 1) & 3) * BE;
    const int d0  = (blk & 1) * BD;

    const float* Ag = emap + ((size_t)b * E_ + e0) * L_;
    const float* Sg = doc  + (size_t)b * L_ * D_ + d0;

    if (t < BE) lens_s[t] = lens[b * E_ + e0 + t];

    // staging coords
    const int a_c4 = t & 15;     // float4 index within 64-k row
    const int a_r  = t >> 4;     // rows a_r and a_r+32
    const int s_db = t & 31;     // d 4-block (32 of them over 128 d)
    const int s_kb = t >> 5;     // k 4-block (16 of them over 64 k)

    // wave coords: 8 waves as 2(e) x 4(d), wave tile 32e x 32d
    const int lane = t & 63;
    const int w    = t >> 6;
    const int eo   = (w & 1) * 32;
    const int dq   = (w >> 1) * 32;
    const int ml   = lane & 15;
    const int kg   = lane >> 4;

    f32x4 acc[2][2] = {};
    f32x4 pa[2], pb[4];

    // preload tile 0
    #pragma unroll
    for (int rr = 0; rr < 2; ++rr)
        pa[rr] = *(const f32x4*)(Ag + (size_t)(a_r + rr * 32) * L_ + a_c4 * 4);
    #pragma unroll
    for (int i = 0; i < 4; ++i)
        pb[i] = *(const f32x4*)(Sg + (size_t)(s_kb * 4 + i) * D_ + s_db * 4);

    for (int kt = 0; kt < NKT; ++kt) {
        // ---- convert & stage to LDS ----
        #pragma unroll
        for (int rr = 0; rr < 2; ++rr) {
            const int row = a_r + rr * 32;
            s16x4 h, l;
            cvt_hilo4(pa[rr], h, l);
            const int col = (((a_c4 >> 1) ^ (row & 7)) << 3) + (a_c4 & 1) * 4;
            *(s16x4*)&As_hi[row][col] = h;
            *(s16x4*)&As_lo[row][col] = l;
        }
        #pragma unroll
        for (int dd = 0; dd < 4; ++dd) {
            const int row = s_db * 4 + dd;               // d index in tile
            f32x4 tv = { pb[0][dd], pb[1][dd], pb[2][dd], pb[3][dd] };  // 4 consecutive k
            s16x4 h, l;
            cvt_hilo4(tv, h, l);
            const int col = (((s_kb >> 1) ^ (s_db & 7)) << 3) + (s_kb & 1) * 4;
            *(s16x4*)&Bs_hi[row][col] = h;
            *(s16x4*)&Bs_lo[row][col] = l;
        }
        __syncthreads();

        // ---- prefetch next tile's globals (completes during MFMA phase) ----
        if (kt + 1 < NKT) {
            const int k0 = (kt + 1) * BK;
            #pragma unroll
            for (int rr = 0; rr < 2; ++rr)
                pa[rr] = *(const f32x4*)(Ag + (size_t)(a_r + rr * 32) * L_ + k0 + a_c4 * 4);
            #pragma unroll
            for (int i = 0; i < 4; ++i)
                pb[i] = *(const f32x4*)(Sg + (size_t)(k0 + s_kb * 4 + i) * D_ + s_db * 4);
        }

        // ---- MFMA over the tile: 3-pass hi/lo split ----
        #pragma unroll
        for (int kc = 0; kc < BK; kc += 32) {
            const int gbase = kc >> 3;   // 0 or 4
            s16x8 ah[2], al[2], bh[2], bl[2];
            #pragma unroll
            for (int mi = 0; mi < 2; ++mi) {
                const int row = eo + mi * 16 + ml;
                const int col = ((gbase + kg) ^ (row & 7)) << 3;
                ah[mi] = *(const s16x8*)&As_hi[row][col];
                al[mi] = *(const s16x8*)&As_lo[row][col];
            }
            #pragma unroll
            for (int ni = 0; ni < 2; ++ni) {
                const int row = dq + ni * 16 + ml;
                const int col = ((gbase + kg) ^ ((row >> 2) & 7)) << 3;
                bh[ni] = *(const s16x8*)&Bs_hi[row][col];
                bl[ni] = *(const s16x8*)&Bs_lo[row][col];
            }
            #pragma unroll
            for (int mi = 0; mi < 2; ++mi)
                #pragma unroll
                for (int ni = 0; ni < 2; ++ni) {
                    acc[mi][ni] = __builtin_amdgcn_mfma_f32_16x16x32_bf16(ah[mi], bh[ni], acc[mi][ni], 0, 0, 0);
                    acc[mi][ni] = __builtin_amdgcn_mfma_f32_16x16x32_bf16(ah[mi], bl[ni], acc[mi][ni], 0, 0, 0);
                    acc[mi][ni] = __builtin_amdgcn_mfma_f32_16x16x32_bf16(al[mi], bh[ni], acc[mi][ni], 0, 0, 0);
                }
        }
        __syncthreads();
    }

    // ---- epilogue: divide by entity_lens, store ----
    #pragma unroll
    for (int mi = 0; mi < 2; ++mi) {
        #pragma unroll
        for (int rr = 0; rr < 4; ++rr) {
            const int er = eo + mi * 16 + kg * 4 + rr;
            const float lv = lens_s[er];
            #pragma unroll
            for (int ni = 0; ni < 2; ++ni) {
                out[((size_t)(b * E_ + e0 + er)) * D_ + d0 + dq + ni * 16 + ml] =
                    acc[mi][ni][rr] / lv;
            }
        }
    }
}

extern "C" void kernel_launch(void* const* d_in, const int* in_sizes, int n_in,
                              void* d_out, int out_size, void* d_ws, size_t ws_size,
                              hipStream_t stream) {
    const float* doc  = (const float*)d_in[0];   // [32][2048][256]
    const float* emap = (const float*)d_in[1];   // [32][256][2048]
    const float* lens = (const float*)d_in[2];   // [32][256]
    float* out = (float*)d_out;                  // [32][256][256]

    dim3 grid(B_ * (E_ / BE) * (D_ / BD));       // 256 workgroups
    dim3 block(512);
    hipLaunchKernelGGL(mean_pool_kernel, grid, block, 0, stream,
                       doc, emap, lens, out);
}

// Round 2
// 173.228 us; speedup vs baseline: 1.1039x; 1.1039x over previous
//
#include <hip/hip_runtime.h>
#include <stdint.h>

#define B_ 32
#define E_ 256
#define L_ 2048
#define D_ 256

#define BE 64
#define BD 128
#define BK 64
#define KS 4                  // k-split factor
#define KCHUNK (L_ / KS)      // 512
#define NKT (KCHUNK / BK)     // 8 k-tiles per block

typedef __attribute__((ext_vector_type(2))) float  f32x2;
typedef __attribute__((ext_vector_type(4))) float  f32x4;
typedef __attribute__((ext_vector_type(4))) short  s16x4;
typedef __attribute__((ext_vector_type(8))) short  s16x8;

// fp32 -> (hi, lo) bf16 pair. hi = truncated bf16(x); lo = bf16(x - hi).
__device__ __forceinline__ void cvt_hilo1(float x, short &h, short &l) {
    unsigned u = __builtin_bit_cast(unsigned, x);
    h = (short)(u >> 16);
    float hf = __builtin_bit_cast(float, u & 0xFFFF0000u);
    unsigned r = __builtin_bit_cast(unsigned, x - hf);
    l = (short)(r >> 16);
}
__device__ __forceinline__ void cvt_hilo4(const f32x4 v, s16x4 &h, s16x4 &l) {
    #pragma unroll
    for (int i = 0; i < 4; ++i) { short hh, ll; cvt_hilo1(v[i], hh, ll); h[i] = hh; l[i] = ll; }
}

__global__ void zero_out_kernel(f32x4* __restrict__ out) {
    out[(size_t)blockIdx.x * 256 + threadIdx.x] = f32x4{0.f, 0.f, 0.f, 0.f};
}

__global__ __launch_bounds__(512, 6)
void mean_pool_kernel(const float* __restrict__ doc,
                      const float* __restrict__ emap,
                      const float* __restrict__ lens,
                      float* __restrict__ out) {
    // A swizzle key: row&7.  B swizzle key: ((row>>1)&3)|(((row>>3)&1)<<2).
    // Both span all 8 col8 groups uniformly for BOTH the write lanes and the
    // read lanes -> all LDS ops at the 32-bank minimum cycle count.
    __shared__ __align__(16) short As_hi[BE][BK];
    __shared__ __align__(16) short As_lo[BE][BK];
    __shared__ __align__(16) short Bs_hi[BD][BK];   // doc^T tile: [d][k]
    __shared__ __align__(16) short Bs_lo[BD][BK];
    __shared__ float lens_s[BE];

    const int t   = threadIdx.x;
    const int blk = blockIdx.x;
    const int ks  = blk & 3;
    const int d0  = ((blk >> 2) & 1) * BD;
    const int e0  = ((blk >> 3) & 3) * BE;
    const int b   = blk >> 5;

    const float* Ag = emap + ((size_t)b * E_ + e0) * L_ + ks * KCHUNK;
    const float* Sg = doc  + (size_t)b * L_ * D_ + (size_t)ks * KCHUNK * D_ + d0;

    if (t < BE) lens_s[t] = lens[b * E_ + e0 + t];

    // A staging coords: 16 lanes per e-row (k-contiguous float4), rows t>>4 and +32
    const int a_c4 = t & 15;
    const int a_r  = t >> 4;
    // B staging coords: micro-tile 8k x 2d per thread
    const int db = t & 63;     // d-pair index (0..63) -> d = db*2, db == lane
    const int kb = t >> 6;     // k-group (0..7)       -> k = kb*8, kb == wave

    // wave coords: 8 waves as 2(e) x 4(d), wave tile 32e x 32d
    const int lane = t & 63;
    const int w    = t >> 6;
    const int eo   = (w & 1) * 32;
    const int dq   = (w >> 1) * 32;
    const int ml   = lane & 15;
    const int kg   = lane >> 4;

    f32x4 acc[2][2] = {};
    f32x4 pa[2];
    f32x2 pb[8];

    // preload tile 0
    #pragma unroll
    for (int rr = 0; rr < 2; ++rr)
        pa[rr] = *(const f32x4*)(Ag + (size_t)(a_r + rr * 32) * L_ + a_c4 * 4);
    #pragma unroll
    for (int i = 0; i < 8; ++i)
        pb[i] = *(const f32x2*)(Sg + (size_t)(kb * 8 + i) * D_ + db * 2);

    for (int kt = 0; kt < NKT; ++kt) {
        // ---- convert & stage to LDS ----
        #pragma unroll
        for (int rr = 0; rr < 2; ++rr) {
            const int row = a_r + rr * 32;
            s16x4 h, l;
            cvt_hilo4(pa[rr], h, l);
            const int col = (((a_c4 >> 1) ^ (row & 7)) << 3) + (a_c4 & 1) * 4;
            *(s16x4*)&As_hi[row][col] = h;
            *(s16x4*)&As_lo[row][col] = l;
        }
        #pragma unroll
        for (int dd = 0; dd < 2; ++dd) {
            const int row = db * 2 + dd;
            s16x8 h, l;
            #pragma unroll
            for (int j = 0; j < 8; ++j) {
                short hh, ll; cvt_hilo1(pb[j][dd], hh, ll);
                h[j] = hh; l[j] = ll;
            }
            const int key = (db & 3) | (((db >> 2) & 1) << 2);   // == ((row>>1)&3)|(((row>>3)&1)<<2)
            const int col = (kb ^ key) << 3;
            *(s16x8*)&Bs_hi[row][col] = h;
            *(s16x8*)&Bs_lo[row][col] = l;
        }
        __syncthreads();

        // ---- prefetch next tile's globals (completes during MFMA phase) ----
        if (kt + 1 < NKT) {
            const int k0 = (kt + 1) * BK;
            #pragma unroll
            for (int rr = 0; rr < 2; ++rr)
                pa[rr] = *(const f32x4*)(Ag + (size_t)(a_r + rr * 32) * L_ + k0 + a_c4 * 4);
            #pragma unroll
            for (int i = 0; i < 8; ++i)
                pb[i] = *(const f32x2*)(Sg + (size_t)(k0 + kb * 8 + i) * D_ + db * 2);
        }

        // ---- MFMA: 3-pass hi/lo split ----
        #pragma unroll
        for (int kc = 0; kc < 2; ++kc) {
            const int gbase = kc * 4;
            s16x8 ah[2], al[2], bh[2], bl[2];
            #pragma unroll
            for (int mi = 0; mi < 2; ++mi) {
                const int row = eo + mi * 16 + ml;
                const int col = ((gbase + kg) ^ (row & 7)) << 3;
                ah[mi] = *(const s16x8*)&As_hi[row][col];
                al[mi] = *(const s16x8*)&As_lo[row][col];
            }
            #pragma unroll
            for (int ni = 0; ni < 2; ++ni) {
                const int row = dq + ni * 16 + ml;
                const int keyB = ((row >> 1) & 3) | (((row >> 3) & 1) << 2);
                const int col  = ((gbase + kg) ^ keyB) << 3;
                bh[ni] = *(const s16x8*)&Bs_hi[row][col];
                bl[ni] = *(const s16x8*)&Bs_lo[row][col];
            }
            #pragma unroll
            for (int mi = 0; mi < 2; ++mi)
                #pragma unroll
                for (int ni = 0; ni < 2; ++ni) {
                    acc[mi][ni] = __builtin_amdgcn_mfma_f32_16x16x32_bf16(ah[mi], bh[ni], acc[mi][ni], 0, 0, 0);
                    acc[mi][ni] = __builtin_amdgcn_mfma_f32_16x16x32_bf16(ah[mi], bl[ni], acc[mi][ni], 0, 0, 0);
                    acc[mi][ni] = __builtin_amdgcn_mfma_f32_16x16x32_bf16(al[mi], bh[ni], acc[mi][ni], 0, 0, 0);
                }
        }
        __syncthreads();
    }

    // ---- epilogue: divide by entity_lens, atomically accumulate k-split partials ----
    #pragma unroll
    for (int mi = 0; mi < 2; ++mi) {
        #pragma unroll
        for (int rr = 0; rr < 4; ++rr) {
            const int er = eo + mi * 16 + kg * 4 + rr;
            const float lv = lens_s[er];
            #pragma unroll
            for (int ni = 0; ni < 2; ++ni) {
                atomicAdd(&out[((size_t)(b * E_ + e0 + er)) * D_ + d0 + dq + ni * 16 + ml],
                          acc[mi][ni][rr] / lv);
            }
        }
    }
}

extern "C" void kernel_launch(void* const* d_in, const int* in_sizes, int n_in,
                              void* d_out, int out_size, void* d_ws, size_t ws_size,
                              hipStream_t stream) {
    const float* doc  = (const float*)d_in[0];   // [32][2048][256]
    const float* emap = (const float*)d_in[1];   // [32][256][2048]
    const float* lens = (const float*)d_in[2];   // [32][256]
    float* out = (float*)d_out;                  // [32][256][256]

    // zero the output (harness poisons it with 0xAA), then accumulate partials
    zero_out_kernel<<<dim3(out_size / (4 * 256)), dim3(256), 0, stream>>>((f32x4*)out);

    dim3 grid(B_ * (E_ / BE) * (D_ / BD) * KS);  // 1024 workgroups
    dim3 block(512);
    hipLaunchKernelGGL(mean_pool_kernel, grid, block, 0, stream,
                       doc, emap, lens, out);
}